// Round 1
// baseline (395.926 us; speedup 1.0000x reference)
//
#include <hip/hip_runtime.h>
#include <hip/hip_bf16.h>
#include <cstdint>
#include <cstddef>

// Problem constants (match reference)
#define N_EDGES_C 800000
#define N_NODES_C 50000
#define IN_CH_C   128
#define KDIM      256   // 2*IN_CH
#define HIDDEN_C  256
#define BM        64    // edges per block; 800000 % 64 == 0 -> 12500 blocks

typedef __attribute__((ext_vector_type(8))) short sh8;
typedef __attribute__((ext_vector_type(4))) float f32x4;

__device__ __forceinline__ unsigned short f2bf(float f) {
  union { float f; unsigned u; } a; a.f = f;
  unsigned r = a.u + 0x7fffu + ((a.u >> 16) & 1u);  // RNE
  return (unsigned short)(r >> 16);
}

// z (fp32, N_NODES x 128) -> bf16 bits, 4 elems/thread
__global__ void cvt_z_kernel(const float* __restrict__ z,
                             unsigned short* __restrict__ zb) {
  int i = blockIdx.x * blockDim.x + threadIdx.x;
  float4 v = reinterpret_cast<const float4*>(z)[i];
  ushort4 o;
  o.x = f2bf(v.x); o.y = f2bf(v.y); o.z = f2bf(v.z); o.w = f2bf(v.w);
  reinterpret_cast<ushort4*>(zb)[i] = o;
}

// W1 [K=256][N=256] fp32 -> W1T [N][K] bf16 (so B-fragments are k-contiguous)
__global__ void cvt_w1t_kernel(const float* __restrict__ w1,
                               unsigned short* __restrict__ w1t) {
  int k = blockIdx.x;    // input row  (coalesced read)
  int n = threadIdx.x;   // output row
  w1t[(size_t)n * KDIM + k] = f2bf(w1[(size_t)k * HIDDEN_C + n]);
}

// Fused: gather -> (ef @ W1 + b1) -> relu -> @W2 + b2 -> sigmoid
// Block: 256 thr (4 waves). Wave w owns N-slice [w*64, w*64+64).
// Block owns 64 edges. MFMA 16x16x32 bf16; A loaded direct from z (bf16 or fp32).
template<bool ZBF>
__global__ __launch_bounds__(256) void decoder_kernel(
    const float* __restrict__ z,
    const unsigned short* __restrict__ zb,
    const int* __restrict__ ei,
    const unsigned short* __restrict__ w1t,
    const float* __restrict__ b1,
    const float* __restrict__ w2,
    const float* __restrict__ b2,
    float* __restrict__ out)
{
  const int tid  = threadIdx.x;
  const int wave = tid >> 6;
  const int lane = tid & 63;
  const int l15  = lane & 15;   // A row / B col / C col within 16-tile
  const int lg   = lane >> 4;   // k-group (A/B), row-quad (C)
  const int base = blockIdx.x * BM;
  const int n0   = wave * 64;
  const int kb   = lg * 8;

  // Edge endpoint indices for the 4 m-tiles this lane touches
  int ridx[4], cidx[4];
#pragma unroll
  for (int mt = 0; mt < 4; ++mt) {
    int e = base + mt * 16 + l15;
    ridx[mt] = ei[e];
    cidx[mt] = ei[N_EDGES_C + e];
  }

  const f32x4 fzero = {0.f, 0.f, 0.f, 0.f};
  f32x4 acc[4][4];
#pragma unroll
  for (int mt = 0; mt < 4; ++mt)
#pragma unroll
    for (int nt = 0; nt < 4; ++nt)
      acc[mt][nt] = fzero;

#pragma unroll
  for (int kk = 0; kk < 8; ++kk) {
    // B fragments for this 32-wide k-chunk: lane reads W1T[n][kOff..kOff+7]
    sh8 bfrag[4];
    const int kOff = kk * 32 + kb;
#pragma unroll
    for (int nt = 0; nt < 4; ++nt)
      bfrag[nt] = *reinterpret_cast<const sh8*>(
          w1t + (size_t)(n0 + nt * 16 + l15) * KDIM + kOff);

#pragma unroll
    for (int mt = 0; mt < 4; ++mt) {
      const int idx  = (kk < 4) ? ridx[mt] : cidx[mt];
      const int zoff = ((kk & 3) * 32) + kb;   // offset within the 128-wide z row
      sh8 af;
      if (ZBF) {
        af = *reinterpret_cast<const sh8*>(zb + (size_t)idx * IN_CH_C + zoff);
      } else {
        const float4* p = reinterpret_cast<const float4*>(
            z + (size_t)idx * IN_CH_C + zoff);
        float4 x0 = p[0], x1 = p[1];
        af[0] = (short)f2bf(x0.x); af[1] = (short)f2bf(x0.y);
        af[2] = (short)f2bf(x0.z); af[3] = (short)f2bf(x0.w);
        af[4] = (short)f2bf(x1.x); af[5] = (short)f2bf(x1.y);
        af[6] = (short)f2bf(x1.z); af[7] = (short)f2bf(x1.w);
      }
#pragma unroll
      for (int nt = 0; nt < 4; ++nt)
        acc[mt][nt] = __builtin_amdgcn_mfma_f32_16x16x32_bf16(
            af, bfrag[nt], acc[mt][nt], 0, 0, 0);
    }
  }

  // Epilogue: bias + relu + W2 GEMV, all fp32 in registers.
  // C layout: col = n0 + nt*16 + (l&15), row = lg*4 + r (edge = base + mt*16 + row)
  float plog[4][4];
#pragma unroll
  for (int mt = 0; mt < 4; ++mt)
#pragma unroll
    for (int r = 0; r < 4; ++r)
      plog[mt][r] = 0.f;

#pragma unroll
  for (int nt = 0; nt < 4; ++nt) {
    const int j = n0 + nt * 16 + l15;
    const float b1v = b1[j];
    const float w2v = w2[j];
#pragma unroll
    for (int mt = 0; mt < 4; ++mt)
#pragma unroll
      for (int r = 0; r < 4; ++r) {
        float v = acc[mt][nt][r] + b1v;
        v = fmaxf(v, 0.f);
        plog[mt][r] = fmaf(v, w2v, plog[mt][r]);
      }
  }

  // Reduce over the 16 columns each wave holds (lanes sharing lg)
#pragma unroll
  for (int s = 1; s < 16; s <<= 1)
#pragma unroll
    for (int mt = 0; mt < 4; ++mt)
#pragma unroll
      for (int r = 0; r < 4; ++r)
        plog[mt][r] += __shfl_xor(plog[mt][r], s, 64);

  // Cross-wave reduce (4 N-slices) via tiny LDS
  __shared__ float red[4][BM];
  if (l15 == 0) {
#pragma unroll
    for (int mt = 0; mt < 4; ++mt)
#pragma unroll
      for (int r = 0; r < 4; ++r)
        red[wave][mt * 16 + lg * 4 + r] = plog[mt][r];
  }
  __syncthreads();
  if (tid < BM) {
    float s = red[0][tid] + red[1][tid] + red[2][tid] + red[3][tid] + b2[0];
    out[base + tid] = 1.f / (1.f + __expf(-s));
  }
}

extern "C" void kernel_launch(void* const* d_in, const int* in_sizes, int n_in,
                              void* d_out, int out_size, void* d_ws, size_t ws_size,
                              hipStream_t stream) {
  const float* z  = (const float*)d_in[0];
  const int*   ei = (const int*)d_in[1];
  const float* W1 = (const float*)d_in[2];
  const float* b1 = (const float*)d_in[3];
  const float* W2 = (const float*)d_in[4];
  const float* b2 = (const float*)d_in[5];
  float* out = (float*)d_out;

  unsigned short* w1t = (unsigned short*)d_ws;
  const size_t w1t_bytes = (size_t)HIDDEN_C * KDIM * sizeof(unsigned short); // 128 KB
  unsigned short* zb = (unsigned short*)((char*)d_ws + w1t_bytes);
  const size_t need = w1t_bytes + (size_t)N_NODES_C * IN_CH_C * sizeof(unsigned short);
  const bool zbf = (ws_size >= need);

  // Prep: W1^T bf16 (always; 128 KB fits any sane ws), z bf16 if ws allows.
  cvt_w1t_kernel<<<KDIM, HIDDEN_C, 0, stream>>>(W1, w1t);
  if (zbf) {
    const int n4 = N_NODES_C * IN_CH_C / 4;              // 1.6M float4 units
    cvt_z_kernel<<<n4 / 256, 256, 0, stream>>>(z, zb);
  }

  dim3 grid(N_EDGES_C / BM);  // 12500
  if (zbf)
    decoder_kernel<true><<<grid, 256, 0, stream>>>(z, zb, ei, w1t, b1, W2, b2, out);
  else
    decoder_kernel<false><<<grid, 256, 0, stream>>>(z, zb, ei, w1t, b1, W2, b2, out);
}

// Round 2
// 242.482 us; speedup vs baseline: 1.6328x; 1.6328x over previous
//
#include <hip/hip_runtime.h>
#include <hip/hip_bf16.h>
#include <cstdint>
#include <cstddef>

// Problem constants (match reference)
#define N_EDGES_C 800000
#define N_NODES_C 50000
#define IN_CH_C   128
#define KDIM      256   // 2*IN_CH
#define HIDDEN_C  256
#define BM        64    // edges per block; 800000 % 64 == 0 -> 12500 blocks
#define LDS_RS    264   // LDS row stride in elems (256 + 8 pad -> bank-balanced)

typedef __attribute__((ext_vector_type(8))) short sh8;
typedef __attribute__((ext_vector_type(4))) float f32x4;

__device__ __forceinline__ unsigned short f2bf(float f) {
  union { float f; unsigned u; } a; a.f = f;
  unsigned r = a.u + 0x7fffu + ((a.u >> 16) & 1u);  // RNE
  return (unsigned short)(r >> 16);
}

// z (fp32, N_NODES x 128) -> bf16 bits, 4 elems/thread
__global__ void cvt_z_kernel(const float* __restrict__ z,
                             unsigned short* __restrict__ zb) {
  int i = blockIdx.x * blockDim.x + threadIdx.x;
  float4 v = reinterpret_cast<const float4*>(z)[i];
  ushort4 o;
  o.x = f2bf(v.x); o.y = f2bf(v.y); o.z = f2bf(v.z); o.w = f2bf(v.w);
  reinterpret_cast<ushort4*>(zb)[i] = o;
}

// W1 [K=256][N=256] fp32 -> W1T [N][K] bf16 (so B-fragments are k-contiguous)
__global__ void cvt_w1t_kernel(const float* __restrict__ w1,
                               unsigned short* __restrict__ w1t) {
  int k = blockIdx.x;    // input row  (coalesced read)
  int n = threadIdx.x;   // output row
  w1t[(size_t)n * KDIM + k] = f2bf(w1[(size_t)k * HIDDEN_C + n]);
}

// Fused: gather -> (ef @ W1 + b1) -> relu -> @W2 + b2 -> sigmoid
// Block: 256 thr (4 waves). Wave w owns N-slice [w*64, w*64+64).
// Block owns 64 edges. A-tile staged in LDS once per block (bulk gather),
// 4 blocks/CU overlap staging<->MFMA across blocks.
template<bool ZBF>
__global__ __launch_bounds__(256, 4) void decoder_kernel(
    const float* __restrict__ z,
    const unsigned short* __restrict__ zb,
    const int* __restrict__ ei,
    const unsigned short* __restrict__ w1t,
    const float* __restrict__ b1,
    const float* __restrict__ w2,
    const float* __restrict__ b2,
    float* __restrict__ out)
{
  __shared__ __align__(16) unsigned short As[BM * LDS_RS];  // 33792 B

  const int tid  = threadIdx.x;
  const int wave = tid >> 6;
  const int lane = tid & 63;
  const int l15  = lane & 15;   // A row / B col / C col within 16-tile
  const int lg   = lane >> 4;   // k-group (A/B), row-quad (C)
  const int base = blockIdx.x * BM;
  const int n0   = wave * 64;
  const int kb   = lg * 8;

  // ---- Stage A-tile: 64 edges x 256 k (concat row||col node rows), bf16 ----
  // Thread t: edge e=t>>2, quarter q=t&3 (node=q>>1, half=q&1): 128 B = 8x16B.
  {
    const int e  = tid >> 2;
    const int q  = tid & 3;
    const int nd = q >> 1;
    const int hf = q & 1;
    const int idx = ei[nd * N_EDGES_C + base + e];
    const int dst = e * LDS_RS + nd * 128 + hf * 64;  // elem offset
    if (ZBF) {
      const unsigned short* src = zb + (size_t)idx * IN_CH_C + hf * 64;
      sh8 t8[8];
#pragma unroll
      for (int i = 0; i < 8; ++i)
        t8[i] = *reinterpret_cast<const sh8*>(src + i * 8);
#pragma unroll
      for (int i = 0; i < 8; ++i)
        *reinterpret_cast<sh8*>(&As[dst + i * 8]) = t8[i];
    } else {
      const float* src = z + (size_t)idx * IN_CH_C + hf * 64;
      float4 tf[16];
#pragma unroll
      for (int i = 0; i < 16; ++i)
        tf[i] = reinterpret_cast<const float4*>(src)[i];
#pragma unroll
      for (int i = 0; i < 8; ++i) {
        sh8 o;
        const float4 x0 = tf[2 * i], x1 = tf[2 * i + 1];
        o[0] = (short)f2bf(x0.x); o[1] = (short)f2bf(x0.y);
        o[2] = (short)f2bf(x0.z); o[3] = (short)f2bf(x0.w);
        o[4] = (short)f2bf(x1.x); o[5] = (short)f2bf(x1.y);
        o[6] = (short)f2bf(x1.z); o[7] = (short)f2bf(x1.w);
        *reinterpret_cast<sh8*>(&As[dst + i * 8]) = o;
      }
    }
  }
  __syncthreads();

  const f32x4 fzero = {0.f, 0.f, 0.f, 0.f};
  f32x4 acc[4][4];
#pragma unroll
  for (int mt = 0; mt < 4; ++mt)
#pragma unroll
    for (int nt = 0; nt < 4; ++nt)
      acc[mt][nt] = fzero;

#pragma unroll
  for (int kk = 0; kk < 8; ++kk) {
    const int kOff = kk * 32 + kb;
    // B fragments for this 32-wide k-chunk: lane reads W1T[n][kOff..kOff+7]
    sh8 bfrag[4];
#pragma unroll
    for (int nt = 0; nt < 4; ++nt)
      bfrag[nt] = *reinterpret_cast<const sh8*>(
          w1t + (size_t)(n0 + nt * 16 + l15) * KDIM + kOff);

#pragma unroll
    for (int mt = 0; mt < 4; ++mt) {
      const sh8 af = *reinterpret_cast<const sh8*>(
          &As[(mt * 16 + l15) * LDS_RS + kOff]);
#pragma unroll
      for (int nt = 0; nt < 4; ++nt)
        acc[mt][nt] = __builtin_amdgcn_mfma_f32_16x16x32_bf16(
            af, bfrag[nt], acc[mt][nt], 0, 0, 0);
    }
  }

  // Epilogue: bias + relu + W2 GEMV, all fp32 in registers.
  // C layout: col = n0 + nt*16 + (l&15), row = lg*4 + r (edge = base + mt*16 + row)
  float plog[4][4];
#pragma unroll
  for (int mt = 0; mt < 4; ++mt)
#pragma unroll
    for (int r = 0; r < 4; ++r)
      plog[mt][r] = 0.f;

#pragma unroll
  for (int nt = 0; nt < 4; ++nt) {
    const int j = n0 + nt * 16 + l15;
    const float b1v = b1[j];
    const float w2v = w2[j];
#pragma unroll
    for (int mt = 0; mt < 4; ++mt)
#pragma unroll
      for (int r = 0; r < 4; ++r) {
        float v = acc[mt][nt][r] + b1v;
        v = fmaxf(v, 0.f);
        plog[mt][r] = fmaf(v, w2v, plog[mt][r]);
      }
  }

  // Reduce over the 16 columns each wave holds (lanes sharing lg)
#pragma unroll
  for (int s = 1; s < 16; s <<= 1)
#pragma unroll
    for (int mt = 0; mt < 4; ++mt)
#pragma unroll
      for (int r = 0; r < 4; ++r)
        plog[mt][r] += __shfl_xor(plog[mt][r], s, 64);

  // Cross-wave reduce (4 N-slices) via tiny LDS
  __shared__ float red[4][BM];
  if (l15 == 0) {
#pragma unroll
    for (int mt = 0; mt < 4; ++mt)
#pragma unroll
      for (int r = 0; r < 4; ++r)
        red[wave][mt * 16 + lg * 4 + r] = plog[mt][r];
  }
  __syncthreads();
  if (tid < BM) {
    float s = red[0][tid] + red[1][tid] + red[2][tid] + red[3][tid] + b2[0];
    out[base + tid] = 1.f / (1.f + __expf(-s));
  }
}

extern "C" void kernel_launch(void* const* d_in, const int* in_sizes, int n_in,
                              void* d_out, int out_size, void* d_ws, size_t ws_size,
                              hipStream_t stream) {
  const float* z  = (const float*)d_in[0];
  const int*   ei = (const int*)d_in[1];
  const float* W1 = (const float*)d_in[2];
  const float* b1 = (const float*)d_in[3];
  const float* W2 = (const float*)d_in[4];
  const float* b2 = (const float*)d_in[5];
  float* out = (float*)d_out;

  unsigned short* w1t = (unsigned short*)d_ws;
  const size_t w1t_bytes = (size_t)HIDDEN_C * KDIM * sizeof(unsigned short); // 128 KB
  unsigned short* zb = (unsigned short*)((char*)d_ws + w1t_bytes);
  const size_t need = w1t_bytes + (size_t)N_NODES_C * IN_CH_C * sizeof(unsigned short);
  const bool zbf = (ws_size >= need);

  // Prep: W1^T bf16 (always; 128 KB fits any sane ws), z bf16 if ws allows.
  cvt_w1t_kernel<<<KDIM, HIDDEN_C, 0, stream>>>(W1, w1t);
  if (zbf) {
    const int n4 = N_NODES_C * IN_CH_C / 4;              // 1.6M float4 units
    cvt_z_kernel<<<n4 / 256, 256, 0, stream>>>(z, zb);
  }

  dim3 grid(N_EDGES_C / BM);  // 12500
  if (zbf)
    decoder_kernel<true><<<grid, 256, 0, stream>>>(z, zb, ei, w1t, b1, W2, b2, out);
  else
    decoder_kernel<false><<<grid, 256, 0, stream>>>(z, zb, ei, w1t, b1, W2, b2, out);
}